// Round 6
// baseline (205.935 us; speedup 1.0000x reference)
//
#include <hip/hip_runtime.h>
#include <hip/hip_bf16.h>

#define IN_F 128
#define OUT_F 16
#define N_HEADS 4
#define OUT_C 64   // OUT_F * N_HEADS
#define ALPHA 0.2f

typedef __attribute__((ext_vector_type(8))) short bf16x8;
typedef __attribute__((ext_vector_type(4))) float f32x4;

// ---- order-preserving float<->uint encoding for atomicMax on floats ----
__device__ __forceinline__ unsigned int enc_f(float f) {
  unsigned int u = __float_as_uint(f);
  return (u & 0x80000000u) ? ~u : (u | 0x80000000u);
}
__device__ __forceinline__ float dec_f(unsigned int u) {
  unsigned int b = (u & 0x80000000u) ? (u & 0x7FFFFFFFu) : ~u;
  return __uint_as_float(b);
}

__device__ __forceinline__ ushort f2bf(float f) {
  union { __hip_bfloat16 b; ushort u; } cv;
  cv.b = __float2bfloat16(f);
  return cv.u;
}
__device__ __forceinline__ float bf2f(ushort u) {
  return __uint_as_float(((unsigned int)u) << 16);
}

__global__ __launch_bounds__(64) void k_init(unsigned int* gmax_s, unsigned int* gmax_d,
                                             float* gsum) {
  int t = threadIdx.x;
  if (t < N_HEADS) {
    gmax_s[t] = enc_f(-3.0e38f);
    gmax_d[t] = enc_f(-3.0e38f);
    gsum[t] = 0.f;
  }
}

// ---- pack W (fp32 [128][64]) into B-fragment lane layout, bf16 ----
__global__ __launch_bounds__(64) void k_pack(const float* __restrict__ W,
                                             uint4* __restrict__ Wp) {
  int lane = threadIdx.x;
  int cl = lane & 15, kg = lane >> 4;
#pragma unroll
  for (int ks = 0; ks < 4; ++ks)
#pragma unroll
    for (int ct = 0; ct < 4; ++ct) {
      int c = ct * 16 + cl;
      int k0 = ks * 32 + kg * 8;
      union { ushort u[8]; uint4 q; } P;
#pragma unroll
      for (int j = 0; j < 8; ++j) P.u[j] = f2bf(W[(k0 + j) * OUT_C + c]);
      Wp[(ks * 4 + ct) * 64 + lane] = P.q;
    }
}

// ---- MFMA GEMM: Whb(bf16) = h @ W; fused scores + per-head max epilogue ----
__global__ __launch_bounds__(256) void k_mm(
    const float* __restrict__ h, const uint4* __restrict__ Wp,
    const float* __restrict__ a_src, const float* __restrict__ a_dst,
    ushort* __restrict__ Whb, float4* __restrict__ ssrc4, float4* __restrict__ sdst4,
    unsigned int* __restrict__ gmax_s, unsigned int* __restrict__ gmax_d,
    int n_nodes)
{
  const int wid = threadIdx.x >> 6, lane = threadIdx.x & 63;
  const int r0 = blockIdx.x * 64 + wid * 16;
  const int arow = r0 + (lane & 15);
  const int rclamp = arow < n_nodes ? arow : n_nodes - 1;
  const float* hrow = h + (size_t)rclamp * IN_F + (lane >> 4) * 8;

  f32x4 acc[4];
#pragma unroll
  for (int ct = 0; ct < 4; ++ct) acc[ct] = (f32x4){0.f, 0.f, 0.f, 0.f};

#pragma unroll
  for (int ks = 0; ks < 4; ++ks) {
    float4 a0 = *(const float4*)(hrow + ks * 32);
    float4 a1 = *(const float4*)(hrow + ks * 32 + 4);
    union { ushort u[8]; bf16x8 v; } A;
    A.u[0] = f2bf(a0.x); A.u[1] = f2bf(a0.y); A.u[2] = f2bf(a0.z); A.u[3] = f2bf(a0.w);
    A.u[4] = f2bf(a1.x); A.u[5] = f2bf(a1.y); A.u[6] = f2bf(a1.z); A.u[7] = f2bf(a1.w);
#pragma unroll
    for (int ct = 0; ct < 4; ++ct) {
      union { uint4 q; bf16x8 v; } B;
      B.q = Wp[(ks * 4 + ct) * 64 + lane];
      acc[ct] = __builtin_amdgcn_mfma_f32_16x16x32_bf16(A.v, B.v, acc[ct], 0, 0, 0);
    }
  }

  // epilogue: C layout col = ct*16 + (lane&15), row = r0 + (lane>>4)*4 + j
  const int cl = lane & 15, g = lane >> 4;
  float as_[4], ad_[4];
#pragma unroll
  for (int ct = 0; ct < 4; ++ct) { as_[ct] = a_src[ct * 16 + cl]; ad_[ct] = a_dst[ct * 16 + cl]; }

  float ms[4], md[4];
#pragma unroll
  for (int ct = 0; ct < 4; ++ct) { ms[ct] = -3.0e38f; md[ct] = -3.0e38f; }

#pragma unroll
  for (int j = 0; j < 4; ++j) {
    int r = r0 + g * 4 + j;
    bool rv = r < n_nodes;
    float ps[4], pd[4];
#pragma unroll
    for (int ct = 0; ct < 4; ++ct) {
      float v = acc[ct][j];
      if (rv) Whb[(size_t)r * OUT_C + ct * 16 + cl] = f2bf(v);
      ps[ct] = v * as_[ct];
      pd[ct] = v * ad_[ct];
    }
#pragma unroll
    for (int o = 1; o < 16; o <<= 1) {
#pragma unroll
      for (int ct = 0; ct < 4; ++ct) {
        ps[ct] += __shfl_xor(ps[ct], o);
        pd[ct] += __shfl_xor(pd[ct], o);
      }
    }
    if (rv && cl == 0) {
      ssrc4[r] = make_float4(ps[0], ps[1], ps[2], ps[3]);
      sdst4[r] = make_float4(pd[0], pd[1], pd[2], pd[3]);
    }
    if (rv) {
#pragma unroll
      for (int ct = 0; ct < 4; ++ct) {
        ms[ct] = fmaxf(ms[ct], ps[ct]);
        md[ct] = fmaxf(md[ct], pd[ct]);
      }
    }
  }
#pragma unroll
  for (int o = 16; o < 64; o <<= 1) {
#pragma unroll
    for (int ct = 0; ct < 4; ++ct) {
      ms[ct] = fmaxf(ms[ct], __shfl_xor(ms[ct], o));
      md[ct] = fmaxf(md[ct], __shfl_xor(md[ct], o));
    }
  }
  __shared__ float wmS[4][4], wmD[4][4];
  if (lane == 0) {
#pragma unroll
    for (int ct = 0; ct < 4; ++ct) { wmS[wid][ct] = ms[ct]; wmD[wid][ct] = md[ct]; }
  }
  __syncthreads();
  if (threadIdx.x < N_HEADS) {
    int t = threadIdx.x;
    float vs = fmaxf(fmaxf(wmS[0][t], wmS[1][t]), fmaxf(wmS[2][t], wmS[3][t]));
    float vd = fmaxf(fmaxf(wmD[0][t], wmD[1][t]), fmaxf(wmD[2][t], wmD[3][t]));
    atomicMax(gmax_s + t, enc_f(vs));
    atomicMax(gmax_d + t, enc_f(vd));
  }
}

// ---- fused: dst histogram + per-head sum of exp(e - M) over all edges ----
__global__ __launch_bounds__(256) void k_hg(
    const int* __restrict__ ei, const float4* __restrict__ ssrc4,
    const float4* __restrict__ sdst4, const unsigned int* __restrict__ gmax_s,
    const unsigned int* __restrict__ gmax_d, int* __restrict__ count,
    float* __restrict__ gsum, int n_edges)
{
  float M[4];
#pragma unroll
  for (int c = 0; c < 4; ++c) {
    float m = dec_f(gmax_s[c]) + dec_f(gmax_d[c]);   // upper bound on edge max
    M[c] = m > 0.f ? m : ALPHA * m;                  // LReLU monotone
  }
  float acc[4] = {0.f, 0.f, 0.f, 0.f};
  const int* srcp = ei;
  const int* dstp = ei + n_edges;
  int n4 = n_edges >> 2;
  int stride = gridDim.x * blockDim.x;
  int tid = blockIdx.x * blockDim.x + threadIdx.x;

  for (int i = tid; i < n4; i += stride) {
    int4 sv = ((const int4*)srcp)[i];
    int4 dv = ((const int4*)dstp)[i];
    int ss[4] = {sv.x, sv.y, sv.z, sv.w};
    int dd[4] = {dv.x, dv.y, dv.z, dv.w};
#pragma unroll
    for (int u = 0; u < 4; ++u) {
      atomicAdd(count + dd[u], 1);
      float4 a = ssrc4[ss[u]];
      float4 b = sdst4[dd[u]];
      float e0 = a.x + b.x; e0 = e0 > 0.f ? e0 : ALPHA * e0;
      float e1 = a.y + b.y; e1 = e1 > 0.f ? e1 : ALPHA * e1;
      float e2 = a.z + b.z; e2 = e2 > 0.f ? e2 : ALPHA * e2;
      float e3 = a.w + b.w; e3 = e3 > 0.f ? e3 : ALPHA * e3;
      acc[0] += __expf(e0 - M[0]); acc[1] += __expf(e1 - M[1]);
      acc[2] += __expf(e2 - M[2]); acc[3] += __expf(e3 - M[3]);
    }
  }
  int e = (n4 << 2) + tid;
  if (e < n_edges) {
    int s = srcp[e], d = dstp[e];
    atomicAdd(count + d, 1);
    float4 a = ssrc4[s];
    float4 b = sdst4[d];
    float e0 = a.x + b.x; e0 = e0 > 0.f ? e0 : ALPHA * e0;
    float e1 = a.y + b.y; e1 = e1 > 0.f ? e1 : ALPHA * e1;
    float e2 = a.z + b.z; e2 = e2 > 0.f ? e2 : ALPHA * e2;
    float e3 = a.w + b.w; e3 = e3 > 0.f ? e3 : ALPHA * e3;
    acc[0] += __expf(e0 - M[0]); acc[1] += __expf(e1 - M[1]);
    acc[2] += __expf(e2 - M[2]); acc[3] += __expf(e3 - M[3]);
  }

  __shared__ float red[4][4];
  int lane = threadIdx.x & 63, wv = threadIdx.x >> 6;
#pragma unroll
  for (int c = 0; c < 4; ++c)
#pragma unroll
    for (int o = 32; o; o >>= 1) acc[c] += __shfl_down(acc[c], o);
  if (lane == 0) { red[wv][0] = acc[0]; red[wv][1] = acc[1]; red[wv][2] = acc[2]; red[wv][3] = acc[3]; }
  __syncthreads();
  if (threadIdx.x < 4) {
    float v = red[0][threadIdx.x] + red[1][threadIdx.x] + red[2][threadIdx.x] + red[3][threadIdx.x];
    atomicAdd(gsum + threadIdx.x, v);
  }
}

// ---- two-level exclusive scan of counts ----
__global__ __launch_bounds__(1024) void k_scan1(
    const int* __restrict__ count, int* __restrict__ offs, int* __restrict__ tsum, int n)
{
  __shared__ int sd[1024];
  int t = threadIdx.x;
  int i = blockIdx.x * 1024 + t;
  int c = (i < n) ? count[i] : 0;
  sd[t] = c;
  __syncthreads();
#pragma unroll
  for (int off = 1; off < 1024; off <<= 1) {
    int v = (t >= off) ? sd[t - off] : 0;
    __syncthreads();
    sd[t] += v;
    __syncthreads();
  }
  if (i < n) offs[i] = sd[t] - c;
  if (t == 1023) tsum[blockIdx.x] = sd[1023];
}

__global__ __launch_bounds__(64) void k_scan2(int* __restrict__ tsum, int* __restrict__ tbase, int nb) {
  if (threadIdx.x == 0) {
    int run = 0;
    for (int b = 0; b < nb; ++b) { tbase[b] = run; run += tsum[b]; }
  }
}

__global__ __launch_bounds__(1024) void k_scan3(
    int* __restrict__ offs, const int* __restrict__ tbase,
    int* __restrict__ cursor, int n, int n_edges)
{
  int i = blockIdx.x * 1024 + threadIdx.x;
  if (i < n) {
    int o = offs[i] + tbase[i >> 10];
    offs[i] = o;
    cursor[i] = o;
  }
  if (i == 0) offs[n] = n_edges;
}

// ---- bucket edges by dst (src only, 4 B payload) ----
__global__ __launch_bounds__(256) void k_bucket(
    const int* __restrict__ ei, int* __restrict__ cursor,
    int* __restrict__ sorted_src, int n_edges)
{
  const int* srcp = ei;
  const int* dstp = ei + n_edges;
  int n4 = n_edges >> 2;
  int stride = gridDim.x * blockDim.x;
  int tid = blockIdx.x * blockDim.x + threadIdx.x;
  for (int i = tid; i < n4; i += stride) {
    int4 sv = ((const int4*)srcp)[i];
    int4 dv = ((const int4*)dstp)[i];
    int ss[4] = {sv.x, sv.y, sv.z, sv.w};
    int dd[4] = {dv.x, dv.y, dv.z, dv.w};
#pragma unroll
    for (int u = 0; u < 4; ++u) {
      int pos = atomicAdd(cursor + dd[u], 1);
      sorted_src[pos] = ss[u];
    }
  }
  int e = (n4 << 2) + tid;
  if (e < n_edges) {
    int pos = atomicAdd(cursor + dstp[e], 1);
    sorted_src[pos] = srcp[e];
  }
}

// ---- aggregate: one wave per dst, lane = channel; weights recomputed ----
__global__ __launch_bounds__(256) void k_agg(
    const int* __restrict__ offs, const int* __restrict__ sorted_src,
    const float* __restrict__ ssrc, const float4* __restrict__ sdst4,
    const ushort* __restrict__ Whb, const unsigned int* __restrict__ gmax_s,
    const unsigned int* __restrict__ gmax_d, const float* __restrict__ gsum,
    float* __restrict__ out, int n_nodes)
{
  int d = blockIdx.x * 4 + (threadIdx.x >> 6);
  if (d >= n_nodes) return;
  int lane = threadIdx.x & 63;
  int head = lane >> 4;
  float m = dec_f(gmax_s[head]) + dec_f(gmax_d[head]);
  float M = m > 0.f ? m : ALPHA * m;
  float inv = 1.f / gsum[head];
  float4 sd4 = sdst4[d];
  float sdh = head == 0 ? sd4.x : head == 1 ? sd4.y : head == 2 ? sd4.z : sd4.w;

  int beg = offs[d], end = offs[d + 1];
  float acc = 0.f;
  int j = beg;
  for (; j + 4 <= end; j += 4) {
    int s[4];
#pragma unroll
    for (int u = 0; u < 4; ++u) s[u] = sorted_src[j + u];
    float w[4];
#pragma unroll
    for (int u = 0; u < 4; ++u) {
      float sc = ssrc[s[u] * N_HEADS + head] + sdh;
      sc = sc > 0.f ? sc : ALPHA * sc;
      w[u] = __expf(sc - M);
    }
#pragma unroll
    for (int u = 0; u < 4; ++u)
      acc += w[u] * bf2f(Whb[(size_t)s[u] * OUT_C + lane]);
  }
  for (; j < end; ++j) {
    int s = sorted_src[j];
    float sc = ssrc[s * N_HEADS + head] + sdh;
    sc = sc > 0.f ? sc : ALPHA * sc;
    acc += __expf(sc - M) * bf2f(Whb[(size_t)s * OUT_C + lane]);
  }
  out[(size_t)d * OUT_C + lane] = fmaxf(acc * inv, 0.f);
}

extern "C" void kernel_launch(void* const* d_in, const int* in_sizes, int n_in,
                              void* d_out, int out_size, void* d_ws, size_t ws_size,
                              hipStream_t stream) {
  const int*   ei    = (const int*)d_in[0];
  const float* h     = (const float*)d_in[1];
  const float* W     = (const float*)d_in[2];
  const float* a_src = (const float*)d_in[3];
  const float* a_dst = (const float*)d_in[4];
  float* out = (float*)d_out;

  const int n_edges = in_sizes[0] / 2;
  const int n_nodes = in_sizes[1] / IN_F;
  const int ntiles  = (n_nodes + 1023) / 1024;

  char* ws = (char*)d_ws;
  size_t off = 0;
  auto alloc = [&](size_t bytes) { void* p = ws + off; off = (off + bytes + 15) & ~(size_t)15; return p; };
  ushort* Whb         = (ushort*)alloc((size_t)n_nodes * OUT_C * 2);
  float* ssrc         = (float*)alloc((size_t)n_nodes * N_HEADS * 4);
  float* sdst         = (float*)alloc((size_t)n_nodes * N_HEADS * 4);
  unsigned int* gmax_s= (unsigned int*)alloc(N_HEADS * 4);
  unsigned int* gmax_d= (unsigned int*)alloc(N_HEADS * 4);
  float* gsum         = (float*)alloc(N_HEADS * 4);
  int* count          = (int*)alloc((size_t)n_nodes * 4);
  int* offs           = (int*)alloc(((size_t)n_nodes + 1) * 4);
  int* tsum           = (int*)alloc((size_t)ntiles * 4);
  int* tbase          = (int*)alloc((size_t)ntiles * 4);
  int* cursor         = (int*)alloc((size_t)n_nodes * 4);
  int* sorted_src     = (int*)alloc((size_t)n_edges * 4);
  uint4* Wp           = (uint4*)alloc(16 * 64 * 16);   // 16 KB packed W

  hipMemsetAsync(count, 0, (size_t)n_nodes * 4, stream);
  k_init<<<1, 64, 0, stream>>>(gmax_s, gmax_d, gsum);
  k_pack<<<1, 64, 0, stream>>>(W, Wp);
  k_mm<<<(n_nodes + 63) / 64, 256, 0, stream>>>(h, Wp, a_src, a_dst, Whb,
      (float4*)ssrc, (float4*)sdst, gmax_s, gmax_d, n_nodes);
  k_hg<<<1024, 256, 0, stream>>>(ei, (const float4*)ssrc, (const float4*)sdst,
                                 gmax_s, gmax_d, count, gsum, n_edges);
  k_scan1<<<ntiles, 1024, 0, stream>>>(count, offs, tsum, n_nodes);
  k_scan2<<<1, 64, 0, stream>>>(tsum, tbase, ntiles);
  k_scan3<<<ntiles, 1024, 0, stream>>>(offs, tbase, cursor, n_nodes, n_edges);
  k_bucket<<<1024, 256, 0, stream>>>(ei, cursor, sorted_src, n_edges);
  k_agg<<<(n_nodes + 3) / 4, 256, 0, stream>>>(offs, sorted_src, ssrc,
      (const float4*)sdst, Whb, gmax_s, gmax_d, gsum, out, n_nodes);
}

// Round 7
// 197.302 us; speedup vs baseline: 1.0438x; 1.0438x over previous
//
#include <hip/hip_runtime.h>
#include <hip/hip_bf16.h>

#define IN_F 128
#define OUT_F 16
#define N_HEADS 4
#define OUT_C 64   // OUT_F * N_HEADS
#define ALPHA 0.2f

typedef __attribute__((ext_vector_type(8))) short bf16x8;
typedef __attribute__((ext_vector_type(4))) float f32x4;

// ---- order-preserving float<->uint encoding for atomicMax on floats ----
__device__ __forceinline__ unsigned int enc_f(float f) {
  unsigned int u = __float_as_uint(f);
  return (u & 0x80000000u) ? ~u : (u | 0x80000000u);
}
__device__ __forceinline__ float dec_f(unsigned int u) {
  unsigned int b = (u & 0x80000000u) ? (u & 0x7FFFFFFFu) : ~u;
  return __uint_as_float(b);
}

__device__ __forceinline__ ushort f2bf(float f) {
  union { __hip_bfloat16 b; ushort u; } cv;
  cv.b = __float2bfloat16(f);
  return cv.u;
}
__device__ __forceinline__ float bf2f(ushort u) {
  return __uint_as_float(((unsigned int)u) << 16);
}

__global__ __launch_bounds__(64) void k_init(unsigned int* gmax_s, unsigned int* gmax_d,
                                             float* gsum) {
  int t = threadIdx.x;
  if (t < N_HEADS) {
    gmax_s[t] = enc_f(-3.0e38f);
    gmax_d[t] = enc_f(-3.0e38f);
    gsum[t] = 0.f;
  }
}

// ---- pack W (fp32 [128][64]) into B-fragment lane layout, bf16 ----
__global__ __launch_bounds__(64) void k_pack(const float* __restrict__ W,
                                             uint4* __restrict__ Wp) {
  int lane = threadIdx.x;
  int cl = lane & 15, kg = lane >> 4;
#pragma unroll
  for (int ks = 0; ks < 4; ++ks)
#pragma unroll
    for (int ct = 0; ct < 4; ++ct) {
      int c = ct * 16 + cl;
      int k0 = ks * 32 + kg * 8;
      union { ushort u[8]; uint4 q; } P;
#pragma unroll
      for (int j = 0; j < 8; ++j) P.u[j] = f2bf(W[(k0 + j) * OUT_C + c]);
      Wp[(ks * 4 + ct) * 64 + lane] = P.q;
    }
}

// ---- MFMA GEMM: Whb(bf16) = h @ W; fused scores + per-head max epilogue ----
__global__ __launch_bounds__(256) void k_mm(
    const float* __restrict__ h, const uint4* __restrict__ Wp,
    const float* __restrict__ a_src, const float* __restrict__ a_dst,
    ushort* __restrict__ Whb, float4* __restrict__ ssrc4, float4* __restrict__ sdst4,
    unsigned int* __restrict__ gmax_s, unsigned int* __restrict__ gmax_d,
    int n_nodes)
{
  const int wid = threadIdx.x >> 6, lane = threadIdx.x & 63;
  const int r0 = blockIdx.x * 64 + wid * 16;
  const int arow = r0 + (lane & 15);
  const int rclamp = arow < n_nodes ? arow : n_nodes - 1;
  const float* hrow = h + (size_t)rclamp * IN_F + (lane >> 4) * 8;

  f32x4 acc[4];
#pragma unroll
  for (int ct = 0; ct < 4; ++ct) acc[ct] = (f32x4){0.f, 0.f, 0.f, 0.f};

#pragma unroll
  for (int ks = 0; ks < 4; ++ks) {
    float4 a0 = *(const float4*)(hrow + ks * 32);
    float4 a1 = *(const float4*)(hrow + ks * 32 + 4);
    union { ushort u[8]; bf16x8 v; } A;
    A.u[0] = f2bf(a0.x); A.u[1] = f2bf(a0.y); A.u[2] = f2bf(a0.z); A.u[3] = f2bf(a0.w);
    A.u[4] = f2bf(a1.x); A.u[5] = f2bf(a1.y); A.u[6] = f2bf(a1.z); A.u[7] = f2bf(a1.w);
#pragma unroll
    for (int ct = 0; ct < 4; ++ct) {
      union { uint4 q; bf16x8 v; } B;
      B.q = Wp[(ks * 4 + ct) * 64 + lane];
      acc[ct] = __builtin_amdgcn_mfma_f32_16x16x32_bf16(A.v, B.v, acc[ct], 0, 0, 0);
    }
  }

  // epilogue: C layout col = ct*16 + (lane&15), row = r0 + (lane>>4)*4 + j
  const int cl = lane & 15, g = lane >> 4;
  float as_[4], ad_[4];
#pragma unroll
  for (int ct = 0; ct < 4; ++ct) { as_[ct] = a_src[ct * 16 + cl]; ad_[ct] = a_dst[ct * 16 + cl]; }

  float ms[4], md[4];
#pragma unroll
  for (int ct = 0; ct < 4; ++ct) { ms[ct] = -3.0e38f; md[ct] = -3.0e38f; }

#pragma unroll
  for (int j = 0; j < 4; ++j) {
    int r = r0 + g * 4 + j;
    bool rv = r < n_nodes;
    float ps[4], pd[4];
#pragma unroll
    for (int ct = 0; ct < 4; ++ct) {
      float v = acc[ct][j];
      if (rv) Whb[(size_t)r * OUT_C + ct * 16 + cl] = f2bf(v);
      ps[ct] = v * as_[ct];
      pd[ct] = v * ad_[ct];
    }
#pragma unroll
    for (int o = 1; o < 16; o <<= 1) {
#pragma unroll
      for (int ct = 0; ct < 4; ++ct) {
        ps[ct] += __shfl_xor(ps[ct], o);
        pd[ct] += __shfl_xor(pd[ct], o);
      }
    }
    if (rv && cl == 0) {
      ssrc4[r] = make_float4(ps[0], ps[1], ps[2], ps[3]);
      sdst4[r] = make_float4(pd[0], pd[1], pd[2], pd[3]);
    }
    if (rv) {
#pragma unroll
      for (int ct = 0; ct < 4; ++ct) {
        ms[ct] = fmaxf(ms[ct], ps[ct]);
        md[ct] = fmaxf(md[ct], pd[ct]);
      }
    }
  }
#pragma unroll
  for (int o = 16; o < 64; o <<= 1) {
#pragma unroll
    for (int ct = 0; ct < 4; ++ct) {
      ms[ct] = fmaxf(ms[ct], __shfl_xor(ms[ct], o));
      md[ct] = fmaxf(md[ct], __shfl_xor(md[ct], o));
    }
  }
  __shared__ float wmS[4][4], wmD[4][4];
  if (lane == 0) {
#pragma unroll
    for (int ct = 0; ct < 4; ++ct) { wmS[wid][ct] = ms[ct]; wmD[wid][ct] = md[ct]; }
  }
  __syncthreads();
  if (threadIdx.x < N_HEADS) {
    int t = threadIdx.x;
    float vs = fmaxf(fmaxf(wmS[0][t], wmS[1][t]), fmaxf(wmS[2][t], wmS[3][t]));
    float vd = fmaxf(fmaxf(wmD[0][t], wmD[1][t]), fmaxf(wmD[2][t], wmD[3][t]));
    atomicMax(gmax_s + t, enc_f(vs));
    atomicMax(gmax_d + t, enc_f(vd));
  }
}

// ---- dst-degree histogram (dst column only: 4 MB) ----
__global__ __launch_bounds__(256) void k_hist(
    const int* __restrict__ dst, int* __restrict__ count, int n_edges)
{
  int n4 = n_edges >> 2;
  int stride = gridDim.x * blockDim.x;
  for (int i = blockIdx.x * blockDim.x + threadIdx.x; i < n4; i += stride) {
    int4 d = ((const int4*)dst)[i];
    atomicAdd(count + d.x, 1);
    atomicAdd(count + d.y, 1);
    atomicAdd(count + d.z, 1);
    atomicAdd(count + d.w, 1);
  }
  int t = blockIdx.x * blockDim.x + threadIdx.x;
  int e = (n4 << 2) + t;
  if (e < n_edges) atomicAdd(count + dst[e], 1);
}

// ---- two-level exclusive scan of counts ----
__global__ __launch_bounds__(1024) void k_scan1(
    const int* __restrict__ count, int* __restrict__ offs, int* __restrict__ tsum, int n)
{
  __shared__ int sd[1024];
  int t = threadIdx.x;
  int i = blockIdx.x * 1024 + t;
  int c = (i < n) ? count[i] : 0;
  sd[t] = c;
  __syncthreads();
#pragma unroll
  for (int off = 1; off < 1024; off <<= 1) {
    int v = (t >= off) ? sd[t - off] : 0;
    __syncthreads();
    sd[t] += v;
    __syncthreads();
  }
  if (i < n) offs[i] = sd[t] - c;
  if (t == 1023) tsum[blockIdx.x] = sd[1023];
}

__global__ __launch_bounds__(64) void k_scan2(int* __restrict__ tsum, int* __restrict__ tbase, int nb) {
  if (threadIdx.x == 0) {
    int run = 0;
    for (int b = 0; b < nb; ++b) { tbase[b] = run; run += tsum[b]; }
  }
}

__global__ __launch_bounds__(1024) void k_scan3(
    int* __restrict__ offs, const int* __restrict__ tbase,
    int* __restrict__ cursor, int n, int n_edges)
{
  int i = blockIdx.x * 1024 + threadIdx.x;
  if (i < n) {
    int o = offs[i] + tbase[i >> 10];
    offs[i] = o;
    cursor[i] = o;
  }
  if (i == 0) offs[n] = n_edges;
}

// ---- XCD-partitioned bucket-by-dst + fused gsum ----
// group g = blockIdx&7 owns dst range [g*chunk,(g+1)*chunk): writes stay in
// one XCD's L2 (round-robin block->XCD mapping), killing dirty-evict amp.
__global__ __launch_bounds__(256) void k_bucket(
    const int* __restrict__ ei, const float4* __restrict__ ssrc4,
    const float4* __restrict__ sdst4, const unsigned int* __restrict__ gmax_s,
    const unsigned int* __restrict__ gmax_d, float* __restrict__ gsum,
    int* __restrict__ cursor, int* __restrict__ sorted_src,
    int n_edges, int n_nodes)
{
  const int g  = blockIdx.x & 7;
  const int lb = blockIdx.x >> 3;
  const int nlb = gridDim.x >> 3;
  const int chunk = (n_nodes + 7) >> 3;
  const int dlo = g * chunk;
  const int dhi = min(n_nodes, dlo + chunk);

  float M[4];
#pragma unroll
  for (int c = 0; c < 4; ++c) {
    float m = dec_f(gmax_s[c]) + dec_f(gmax_d[c]);
    M[c] = m > 0.f ? m : ALPHA * m;
  }
  float acc[4] = {0.f, 0.f, 0.f, 0.f};

  const int* srcp = ei;
  const int* dstp = ei + n_edges;
  int n4 = n_edges >> 2;
  int stride = nlb * 256;

  for (int i = lb * 256 + threadIdx.x; i < n4; i += stride) {
    int4 sv = ((const int4*)srcp)[i];
    int4 dv = ((const int4*)dstp)[i];
    int ss[4] = {sv.x, sv.y, sv.z, sv.w};
    int dd[4] = {dv.x, dv.y, dv.z, dv.w};
#pragma unroll
    for (int u = 0; u < 4; ++u) {
      int d = dd[u];
      if (d >= dlo && d < dhi) {
        int s = ss[u];
        float4 a = ssrc4[s];
        float4 b = sdst4[d];
        float e0 = a.x + b.x; e0 = e0 > 0.f ? e0 : ALPHA * e0;
        float e1 = a.y + b.y; e1 = e1 > 0.f ? e1 : ALPHA * e1;
        float e2 = a.z + b.z; e2 = e2 > 0.f ? e2 : ALPHA * e2;
        float e3 = a.w + b.w; e3 = e3 > 0.f ? e3 : ALPHA * e3;
        acc[0] += __expf(e0 - M[0]); acc[1] += __expf(e1 - M[1]);
        acc[2] += __expf(e2 - M[2]); acc[3] += __expf(e3 - M[3]);
        int pos = atomicAdd(cursor + d, 1);
        sorted_src[pos] = s;
      }
    }
  }
  // tail (n_edges % 4): block 0 of each group checks its range
  if (lb == 0) {
    int e = (n4 << 2) + threadIdx.x;
    if (e < n_edges) {
      int d = dstp[e];
      if (d >= dlo && d < dhi) {
        int s = srcp[e];
        float4 a = ssrc4[s];
        float4 b = sdst4[d];
        float e0 = a.x + b.x; e0 = e0 > 0.f ? e0 : ALPHA * e0;
        float e1 = a.y + b.y; e1 = e1 > 0.f ? e1 : ALPHA * e1;
        float e2 = a.z + b.z; e2 = e2 > 0.f ? e2 : ALPHA * e2;
        float e3 = a.w + b.w; e3 = e3 > 0.f ? e3 : ALPHA * e3;
        acc[0] += __expf(e0 - M[0]); acc[1] += __expf(e1 - M[1]);
        acc[2] += __expf(e2 - M[2]); acc[3] += __expf(e3 - M[3]);
        int pos = atomicAdd(cursor + d, 1);
        sorted_src[pos] = s;
      }
    }
  }

  __shared__ float red[4][4];
  int lane = threadIdx.x & 63, wv = threadIdx.x >> 6;
#pragma unroll
  for (int c = 0; c < 4; ++c)
#pragma unroll
    for (int o = 32; o; o >>= 1) acc[c] += __shfl_down(acc[c], o);
  if (lane == 0) { red[wv][0] = acc[0]; red[wv][1] = acc[1]; red[wv][2] = acc[2]; red[wv][3] = acc[3]; }
  __syncthreads();
  if (threadIdx.x < 4) {
    float v = red[0][threadIdx.x] + red[1][threadIdx.x] + red[2][threadIdx.x] + red[3][threadIdx.x];
    atomicAdd(gsum + threadIdx.x, v);
  }
}

// ---- aggregate: one wave per dst, lane = channel; weights recomputed ----
__global__ __launch_bounds__(256) void k_agg(
    const int* __restrict__ offs, const int* __restrict__ sorted_src,
    const float* __restrict__ ssrc, const float4* __restrict__ sdst4,
    const ushort* __restrict__ Whb, const unsigned int* __restrict__ gmax_s,
    const unsigned int* __restrict__ gmax_d, const float* __restrict__ gsum,
    float* __restrict__ out, int n_nodes)
{
  int d = blockIdx.x * 4 + (threadIdx.x >> 6);
  if (d >= n_nodes) return;
  int lane = threadIdx.x & 63;
  int head = lane >> 4;
  float m = dec_f(gmax_s[head]) + dec_f(gmax_d[head]);
  float M = m > 0.f ? m : ALPHA * m;
  float inv = 1.f / gsum[head];
  float4 sd4 = sdst4[d];
  float sdh = head == 0 ? sd4.x : head == 1 ? sd4.y : head == 2 ? sd4.z : sd4.w;

  int beg = offs[d], end = offs[d + 1];
  float acc = 0.f;
  int j = beg;
  for (; j + 4 <= end; j += 4) {
    int s[4];
#pragma unroll
    for (int u = 0; u < 4; ++u) s[u] = sorted_src[j + u];
    float w[4];
#pragma unroll
    for (int u = 0; u < 4; ++u) {
      float sc = ssrc[s[u] * N_HEADS + head] + sdh;
      sc = sc > 0.f ? sc : ALPHA * sc;
      w[u] = __expf(sc - M);
    }
#pragma unroll
    for (int u = 0; u < 4; ++u)
      acc += w[u] * bf2f(Whb[(size_t)s[u] * OUT_C + lane]);
  }
  for (; j < end; ++j) {
    int s = sorted_src[j];
    float sc = ssrc[s * N_HEADS + head] + sdh;
    sc = sc > 0.f ? sc : ALPHA * sc;
    acc += __expf(sc - M) * bf2f(Whb[(size_t)s * OUT_C + lane]);
  }
  out[(size_t)d * OUT_C + lane] = fmaxf(acc * inv, 0.f);
}

extern "C" void kernel_launch(void* const* d_in, const int* in_sizes, int n_in,
                              void* d_out, int out_size, void* d_ws, size_t ws_size,
                              hipStream_t stream) {
  const int*   ei    = (const int*)d_in[0];
  const float* h     = (const float*)d_in[1];
  const float* W     = (const float*)d_in[2];
  const float* a_src = (const float*)d_in[3];
  const float* a_dst = (const float*)d_in[4];
  float* out = (float*)d_out;

  const int n_edges = in_sizes[0] / 2;
  const int n_nodes = in_sizes[1] / IN_F;
  const int ntiles  = (n_nodes + 1023) / 1024;

  char* ws = (char*)d_ws;
  size_t off = 0;
  auto alloc = [&](size_t bytes) { void* p = ws + off; off = (off + bytes + 15) & ~(size_t)15; return p; };
  ushort* Whb         = (ushort*)alloc((size_t)n_nodes * OUT_C * 2);
  float* ssrc         = (float*)alloc((size_t)n_nodes * N_HEADS * 4);
  float* sdst         = (float*)alloc((size_t)n_nodes * N_HEADS * 4);
  unsigned int* gmax_s= (unsigned int*)alloc(N_HEADS * 4);
  unsigned int* gmax_d= (unsigned int*)alloc(N_HEADS * 4);
  float* gsum         = (float*)alloc(N_HEADS * 4);
  int* count          = (int*)alloc((size_t)n_nodes * 4);
  int* offs           = (int*)alloc(((size_t)n_nodes + 1) * 4);
  int* tsum           = (int*)alloc((size_t)ntiles * 4);
  int* tbase          = (int*)alloc((size_t)ntiles * 4);
  int* cursor         = (int*)alloc((size_t)n_nodes * 4);
  int* sorted_src     = (int*)alloc((size_t)n_edges * 4);
  uint4* Wp           = (uint4*)alloc(16 * 64 * 16);   // 16 KB packed W

  hipMemsetAsync(count, 0, (size_t)n_nodes * 4, stream);
  k_init<<<1, 64, 0, stream>>>(gmax_s, gmax_d, gsum);
  k_pack<<<1, 64, 0, stream>>>(W, Wp);
  k_hist<<<1024, 256, 0, stream>>>(ei + n_edges, count, n_edges);
  k_mm<<<(n_nodes + 63) / 64, 256, 0, stream>>>(h, Wp, a_src, a_dst, Whb,
      (float4*)ssrc, (float4*)sdst, gmax_s, gmax_d, n_nodes);
  k_scan1<<<ntiles, 1024, 0, stream>>>(count, offs, tsum, n_nodes);
  k_scan2<<<1, 64, 0, stream>>>(tsum, tbase, ntiles);
  k_scan3<<<ntiles, 1024, 0, stream>>>(offs, tbase, cursor, n_nodes, n_edges);
  k_bucket<<<1024, 256, 0, stream>>>(ei, (const float4*)ssrc, (const float4*)sdst,
      gmax_s, gmax_d, gsum, cursor, sorted_src, n_edges, n_nodes);
  k_agg<<<(n_nodes + 3) / 4, 256, 0, stream>>>(offs, sorted_src, ssrc,
      (const float4*)sdst, Whb, gmax_s, gmax_d, gsum, out, n_nodes);
}

// Round 8
// 194.127 us; speedup vs baseline: 1.0608x; 1.0164x over previous
//
#include <hip/hip_runtime.h>
#include <hip/hip_bf16.h>

#define IN_F 128
#define OUT_F 16
#define N_HEADS 4
#define OUT_C 64   // OUT_F * N_HEADS
#define ALPHA 0.2f
#define EPB 1024   // edges per partition block

typedef __attribute__((ext_vector_type(8))) short bf16x8;
typedef __attribute__((ext_vector_type(4))) float f32x4;

// ---- order-preserving float<->uint encoding for atomicMax on floats ----
__device__ __forceinline__ unsigned int enc_f(float f) {
  unsigned int u = __float_as_uint(f);
  return (u & 0x80000000u) ? ~u : (u | 0x80000000u);
}
__device__ __forceinline__ float dec_f(unsigned int u) {
  unsigned int b = (u & 0x80000000u) ? (u & 0x7FFFFFFFu) : ~u;
  return __uint_as_float(b);
}

__device__ __forceinline__ ushort f2bf(float f) {
  union { __hip_bfloat16 b; ushort u; } cv;
  cv.b = __float2bfloat16(f);
  return cv.u;
}
__device__ __forceinline__ float bf2f(ushort u) {
  return __uint_as_float(((unsigned int)u) << 16);
}

__global__ __launch_bounds__(64) void k_init(unsigned int* gmax_s, unsigned int* gmax_d,
                                             float* gsum) {
  int t = threadIdx.x;
  if (t < N_HEADS) {
    gmax_s[t] = enc_f(-3.0e38f);
    gmax_d[t] = enc_f(-3.0e38f);
    gsum[t] = 0.f;
  }
}

// ---- pack W (fp32 [128][64]) into B-fragment lane layout, bf16 ----
__global__ __launch_bounds__(64) void k_pack(const float* __restrict__ W,
                                             uint4* __restrict__ Wp) {
  int lane = threadIdx.x;
  int cl = lane & 15, kg = lane >> 4;
#pragma unroll
  for (int ks = 0; ks < 4; ++ks)
#pragma unroll
    for (int ct = 0; ct < 4; ++ct) {
      int c = ct * 16 + cl;
      int k0 = ks * 32 + kg * 8;
      union { ushort u[8]; uint4 q; } P;
#pragma unroll
      for (int j = 0; j < 8; ++j) P.u[j] = f2bf(W[(k0 + j) * OUT_C + c]);
      Wp[(ks * 4 + ct) * 64 + lane] = P.q;
    }
}

// ---- MFMA GEMM: Whb(bf16) = h @ W; fused scores + per-head max epilogue ----
__global__ __launch_bounds__(256) void k_mm(
    const float* __restrict__ h, const uint4* __restrict__ Wp,
    const float* __restrict__ a_src, const float* __restrict__ a_dst,
    ushort* __restrict__ Whb, float4* __restrict__ ssrc4, float4* __restrict__ sdst4,
    unsigned int* __restrict__ gmax_s, unsigned int* __restrict__ gmax_d,
    int n_nodes)
{
  const int wid = threadIdx.x >> 6, lane = threadIdx.x & 63;
  const int r0 = blockIdx.x * 64 + wid * 16;
  const int arow = r0 + (lane & 15);
  const int rclamp = arow < n_nodes ? arow : n_nodes - 1;
  const float* hrow = h + (size_t)rclamp * IN_F + (lane >> 4) * 8;

  f32x4 acc[4];
#pragma unroll
  for (int ct = 0; ct < 4; ++ct) acc[ct] = (f32x4){0.f, 0.f, 0.f, 0.f};

#pragma unroll
  for (int ks = 0; ks < 4; ++ks) {
    float4 a0 = *(const float4*)(hrow + ks * 32);
    float4 a1 = *(const float4*)(hrow + ks * 32 + 4);
    union { ushort u[8]; bf16x8 v; } A;
    A.u[0] = f2bf(a0.x); A.u[1] = f2bf(a0.y); A.u[2] = f2bf(a0.z); A.u[3] = f2bf(a0.w);
    A.u[4] = f2bf(a1.x); A.u[5] = f2bf(a1.y); A.u[6] = f2bf(a1.z); A.u[7] = f2bf(a1.w);
#pragma unroll
    for (int ct = 0; ct < 4; ++ct) {
      union { uint4 q; bf16x8 v; } B;
      B.q = Wp[(ks * 4 + ct) * 64 + lane];
      acc[ct] = __builtin_amdgcn_mfma_f32_16x16x32_bf16(A.v, B.v, acc[ct], 0, 0, 0);
    }
  }

  const int cl = lane & 15, g = lane >> 4;
  float as_[4], ad_[4];
#pragma unroll
  for (int ct = 0; ct < 4; ++ct) { as_[ct] = a_src[ct * 16 + cl]; ad_[ct] = a_dst[ct * 16 + cl]; }

  float ms[4], md[4];
#pragma unroll
  for (int ct = 0; ct < 4; ++ct) { ms[ct] = -3.0e38f; md[ct] = -3.0e38f; }

#pragma unroll
  for (int j = 0; j < 4; ++j) {
    int r = r0 + g * 4 + j;
    bool rv = r < n_nodes;
    float ps[4], pd[4];
#pragma unroll
    for (int ct = 0; ct < 4; ++ct) {
      float v = acc[ct][j];
      if (rv) Whb[(size_t)r * OUT_C + ct * 16 + cl] = f2bf(v);
      ps[ct] = v * as_[ct];
      pd[ct] = v * ad_[ct];
    }
#pragma unroll
    for (int o = 1; o < 16; o <<= 1) {
#pragma unroll
      for (int ct = 0; ct < 4; ++ct) {
        ps[ct] += __shfl_xor(ps[ct], o);
        pd[ct] += __shfl_xor(pd[ct], o);
      }
    }
    if (rv && cl == 0) {
      ssrc4[r] = make_float4(ps[0], ps[1], ps[2], ps[3]);
      sdst4[r] = make_float4(pd[0], pd[1], pd[2], pd[3]);
    }
    if (rv) {
#pragma unroll
      for (int ct = 0; ct < 4; ++ct) {
        ms[ct] = fmaxf(ms[ct], ps[ct]);
        md[ct] = fmaxf(md[ct], pd[ct]);
      }
    }
  }
#pragma unroll
  for (int o = 16; o < 64; o <<= 1) {
#pragma unroll
    for (int ct = 0; ct < 4; ++ct) {
      ms[ct] = fmaxf(ms[ct], __shfl_xor(ms[ct], o));
      md[ct] = fmaxf(md[ct], __shfl_xor(md[ct], o));
    }
  }
  __shared__ float wmS[4][4], wmD[4][4];
  if (lane == 0) {
#pragma unroll
    for (int ct = 0; ct < 4; ++ct) { wmS[wid][ct] = ms[ct]; wmD[wid][ct] = md[ct]; }
  }
  __syncthreads();
  if (threadIdx.x < N_HEADS) {
    int t = threadIdx.x;
    float vs = fmaxf(fmaxf(wmS[0][t], wmS[1][t]), fmaxf(wmS[2][t], wmS[3][t]));
    float vd = fmaxf(fmaxf(wmD[0][t], wmD[1][t]), fmaxf(wmD[2][t], wmD[3][t]));
    atomicMax(gmax_s + t, enc_f(vs));
    atomicMax(gmax_d + t, enc_f(vd));
  }
}

// ---- pass A: per-block LDS 8-bucket counting sort + dst histogram ----
// bucket = coarse dst range (locality hint only; correctness doesn't depend
// on the bucket mapping being exact). Writes: coalesced, block-private span.
__global__ __launch_bounds__(256) void k_part(
    const int* __restrict__ ei, int* __restrict__ count,
    int2* __restrict__ pairs, int* __restrict__ bcnt,
    int n_edges, float inv_chunk)
{
  const int base = blockIdx.x * EPB;
  const int n = min(EPB, n_edges - base);
  const int t = threadIdx.x;
  __shared__ int lh[8], lo[8];
  __shared__ int2 buf[EPB];   // 8 KB
  if (t < 8) lh[t] = 0;
  __syncthreads();

  int s_[4], d_[4], b_[4];
  bool v_[4];
#pragma unroll
  for (int k = 0; k < 4; ++k) {
    int idx = k * 256 + t;
    v_[k] = idx < n;
    if (v_[k]) {
      s_[k] = ei[base + idx];
      d_[k] = ei[n_edges + base + idx];
      int b = (int)((float)d_[k] * inv_chunk);
      b = b < 0 ? 0 : (b > 7 ? 7 : b);
      b_[k] = b;
      atomicAdd(&lh[b], 1);
      atomicAdd(count + d_[k], 1);
    }
  }
  __syncthreads();
  if (t == 0) {
    int run = 0;
#pragma unroll
    for (int b = 0; b < 8; ++b) { lo[b] = run; run += lh[b]; }
  }
  __syncthreads();
#pragma unroll
  for (int k = 0; k < 4; ++k) {
    if (v_[k]) {
      int pos = atomicAdd(&lo[b_[k]], 1);
      buf[pos] = make_int2(s_[k], d_[k]);
    }
  }
  __syncthreads();
  for (int i = t; i < n; i += 256) pairs[base + i] = buf[i];
  if (t < 8) bcnt[blockIdx.x * 8 + t] = lh[t];
}

// ---- two-level exclusive scan of counts ----
__global__ __launch_bounds__(1024) void k_scan1(
    const int* __restrict__ count, int* __restrict__ offs, int* __restrict__ tsum, int n)
{
  __shared__ int sd[1024];
  int t = threadIdx.x;
  int i = blockIdx.x * 1024 + t;
  int c = (i < n) ? count[i] : 0;
  sd[t] = c;
  __syncthreads();
#pragma unroll
  for (int off = 1; off < 1024; off <<= 1) {
    int v = (t >= off) ? sd[t - off] : 0;
    __syncthreads();
    sd[t] += v;
    __syncthreads();
  }
  if (i < n) offs[i] = sd[t] - c;
  if (t == 1023) tsum[blockIdx.x] = sd[1023];
}

__global__ __launch_bounds__(64) void k_scan2(int* __restrict__ tsum, int* __restrict__ tbase, int nb) {
  if (threadIdx.x == 0) {
    int run = 0;
    for (int b = 0; b < nb; ++b) { tbase[b] = run; run += tsum[b]; }
  }
}

__global__ __launch_bounds__(1024) void k_scan3(
    int* __restrict__ offs, const int* __restrict__ tbase,
    int* __restrict__ cursor, int n, int n_edges)
{
  int i = blockIdx.x * 1024 + threadIdx.x;
  if (i < n) {
    int o = offs[i] + tbase[i >> 10];
    offs[i] = o;
    cursor[i] = o;
  }
  if (i == 0) offs[n] = n_edges;
}

// ---- pass B: XCD-partitioned scatter from bucketed runs + fused gsum ----
__global__ __launch_bounds__(256) void k_scat(
    const int2* __restrict__ pairs, const int* __restrict__ bcnt,
    const float4* __restrict__ ssrc4, const float4* __restrict__ sdst4,
    const unsigned int* __restrict__ gmax_s, const unsigned int* __restrict__ gmax_d,
    float* __restrict__ gsum, int* __restrict__ cursor, int* __restrict__ sorted_src,
    int nba)
{
  const int g  = blockIdx.x & 7;
  const int lb = blockIdx.x >> 3;
  const int nlb = gridDim.x >> 3;

  float M[4];
#pragma unroll
  for (int c = 0; c < 4; ++c) {
    float m = dec_f(gmax_s[c]) + dec_f(gmax_d[c]);
    M[c] = m > 0.f ? m : ALPHA * m;
  }
  float acc[4] = {0.f, 0.f, 0.f, 0.f};

  for (int i = lb; i < nba; i += nlb) {
    int pre = 0, cnt = 0;
#pragma unroll
    for (int b = 0; b < 8; ++b) {
      int c = bcnt[i * 8 + b];
      pre += (b < g) ? c : 0;
      cnt = (b == g) ? c : cnt;
    }
    const int2* run = pairs + (size_t)i * EPB + pre;
    for (int j = threadIdx.x; j < cnt; j += 256) {
      int2 p = run[j];
      float4 a = ssrc4[p.x];
      float4 b4 = sdst4[p.y];
      float e0 = a.x + b4.x; e0 = e0 > 0.f ? e0 : ALPHA * e0;
      float e1 = a.y + b4.y; e1 = e1 > 0.f ? e1 : ALPHA * e1;
      float e2 = a.z + b4.z; e2 = e2 > 0.f ? e2 : ALPHA * e2;
      float e3 = a.w + b4.w; e3 = e3 > 0.f ? e3 : ALPHA * e3;
      acc[0] += __expf(e0 - M[0]); acc[1] += __expf(e1 - M[1]);
      acc[2] += __expf(e2 - M[2]); acc[3] += __expf(e3 - M[3]);
      int pos = atomicAdd(cursor + p.y, 1);
      sorted_src[pos] = p.x;
    }
  }

  __shared__ float red[4][4];
  int lane = threadIdx.x & 63, wv = threadIdx.x >> 6;
#pragma unroll
  for (int c = 0; c < 4; ++c)
#pragma unroll
    for (int o = 32; o; o >>= 1) acc[c] += __shfl_down(acc[c], o);
  if (lane == 0) { red[wv][0] = acc[0]; red[wv][1] = acc[1]; red[wv][2] = acc[2]; red[wv][3] = acc[3]; }
  __syncthreads();
  if (threadIdx.x < 4) {
    float v = red[0][threadIdx.x] + red[1][threadIdx.x] + red[2][threadIdx.x] + red[3][threadIdx.x];
    atomicAdd(gsum + threadIdx.x, v);
  }
}

// ---- aggregate: one wave per dst, lane = channel; weights recomputed ----
__global__ __launch_bounds__(256) void k_agg(
    const int* __restrict__ offs, const int* __restrict__ sorted_src,
    const float* __restrict__ ssrc, const float4* __restrict__ sdst4,
    const ushort* __restrict__ Whb, const unsigned int* __restrict__ gmax_s,
    const unsigned int* __restrict__ gmax_d, const float* __restrict__ gsum,
    float* __restrict__ out, int n_nodes)
{
  int d = blockIdx.x * 4 + (threadIdx.x >> 6);
  if (d >= n_nodes) return;
  int lane = threadIdx.x & 63;
  int head = lane >> 4;
  float m = dec_f(gmax_s[head]) + dec_f(gmax_d[head]);
  float M = m > 0.f ? m : ALPHA * m;
  float inv = 1.f / gsum[head];
  float4 sd4 = sdst4[d];
  float sdh = head == 0 ? sd4.x : head == 1 ? sd4.y : head == 2 ? sd4.z : sd4.w;

  int beg = offs[d], end = offs[d + 1];
  float acc = 0.f;
  int j = beg;
  for (; j + 4 <= end; j += 4) {
    int s[4];
#pragma unroll
    for (int u = 0; u < 4; ++u) s[u] = sorted_src[j + u];
    float w[4];
#pragma unroll
    for (int u = 0; u < 4; ++u) {
      float sc = ssrc[s[u] * N_HEADS + head] + sdh;
      sc = sc > 0.f ? sc : ALPHA * sc;
      w[u] = __expf(sc - M);
    }
#pragma unroll
    for (int u = 0; u < 4; ++u)
      acc += w[u] * bf2f(Whb[(size_t)s[u] * OUT_C + lane]);
  }
  for (; j < end; ++j) {
    int s = sorted_src[j];
    float sc = ssrc[s * N_HEADS + head] + sdh;
    sc = sc > 0.f ? sc : ALPHA * sc;
    acc += __expf(sc - M) * bf2f(Whb[(size_t)s * OUT_C + lane]);
  }
  out[(size_t)d * OUT_C + lane] = fmaxf(acc * inv, 0.f);
}

extern "C" void kernel_launch(void* const* d_in, const int* in_sizes, int n_in,
                              void* d_out, int out_size, void* d_ws, size_t ws_size,
                              hipStream_t stream) {
  const int*   ei    = (const int*)d_in[0];
  const float* h     = (const float*)d_in[1];
  const float* W     = (const float*)d_in[2];
  const float* a_src = (const float*)d_in[3];
  const float* a_dst = (const float*)d_in[4];
  float* out = (float*)d_out;

  const int n_edges = in_sizes[0] / 2;
  const int n_nodes = in_sizes[1] / IN_F;
  const int ntiles  = (n_nodes + 1023) / 1024;
  const int nba     = (n_edges + EPB - 1) / EPB;
  const int chunk   = (n_nodes + 7) / 8;
  const float inv_chunk = 1.0f / (float)chunk;

  char* ws = (char*)d_ws;
  size_t off = 0;
  auto alloc = [&](size_t bytes) { void* p = ws + off; off = (off + bytes + 15) & ~(size_t)15; return p; };
  ushort* Whb         = (ushort*)alloc((size_t)n_nodes * OUT_C * 2);
  float* ssrc         = (float*)alloc((size_t)n_nodes * N_HEADS * 4);
  float* sdst         = (float*)alloc((size_t)n_nodes * N_HEADS * 4);
  unsigned int* gmax_s= (unsigned int*)alloc(N_HEADS * 4);
  unsigned int* gmax_d= (unsigned int*)alloc(N_HEADS * 4);
  float* gsum         = (float*)alloc(N_HEADS * 4);
  int* count          = (int*)alloc((size_t)n_nodes * 4);
  int* offs           = (int*)alloc(((size_t)n_nodes + 1) * 4);
  int* tsum           = (int*)alloc((size_t)ntiles * 4);
  int* tbase          = (int*)alloc((size_t)ntiles * 4);
  int* cursor         = (int*)alloc((size_t)n_nodes * 4);
  int* sorted_src     = (int*)alloc((size_t)n_edges * 4);
  int2* pairs         = (int2*)alloc((size_t)nba * EPB * 8);
  int* bcnt           = (int*)alloc((size_t)nba * 8 * 4);
  uint4* Wp           = (uint4*)alloc(16 * 64 * 16);   // 16 KB packed W

  hipMemsetAsync(count, 0, (size_t)n_nodes * 4, stream);
  k_init<<<1, 64, 0, stream>>>(gmax_s, gmax_d, gsum);
  k_pack<<<1, 64, 0, stream>>>(W, Wp);
  k_part<<<nba, 256, 0, stream>>>(ei, count, pairs, bcnt, n_edges, inv_chunk);
  k_mm<<<(n_nodes + 63) / 64, 256, 0, stream>>>(h, Wp, a_src, a_dst, Whb,
      (float4*)ssrc, (float4*)sdst, gmax_s, gmax_d, n_nodes);
  k_scan1<<<ntiles, 1024, 0, stream>>>(count, offs, tsum, n_nodes);
  k_scan2<<<1, 64, 0, stream>>>(tsum, tbase, ntiles);
  k_scan3<<<ntiles, 1024, 0, stream>>>(offs, tbase, cursor, n_nodes, n_edges);
  k_scat<<<1024, 256, 0, stream>>>(pairs, bcnt, (const float4*)ssrc, (const float4*)sdst,
      gmax_s, gmax_d, gsum, cursor, sorted_src, nba);
  k_agg<<<(n_nodes + 3) / 4, 256, 0, stream>>>(offs, sorted_src, ssrc,
      (const float4*)sdst, Whb, gmax_s, gmax_d, gsum, out, n_nodes);
}